// Round 2
// baseline (598.338 us; speedup 1.0000x reference)
//
#include <hip/hip_runtime.h>

#define N_NODES 4096
#define C_CH    128
#define NSPEC   10
#define NCUB    165
#define NQUAD   45
#define NMONO   219   // 165 cubic + 45 quad + 9 linear

// ---- workspace layout (bytes); total = 13,049,824 (~12.5 MB) ----
#define WS_CNT    0            // 10 ints (species counts)
#define WS_LIST   256          // 10*4096 ints = 163840
#define WS_U3SYM  164096       // 4og*165*4k floats = 10560
#define WS_U2SYM  174656       // 4og*45*2k  floats = 1440
#define WS_COEFF  176096       // 1280*(219*4) floats = 4485120
#define WS_F      4661216      // 4096*128*4 floats  = 8388608

// ---------------------------------------------------------------------------
// Kernel 1: zero species counters + build permutation-symmetrized U3/U2.
// ---------------------------------------------------------------------------
__global__ void k_prep(const float* __restrict__ U3_0e, const float* __restrict__ U3_1o,
                       const float* __restrict__ U2_0e, const float* __restrict__ U2_1o,
                       int* __restrict__ cnt, float* __restrict__ U3sym,
                       float* __restrict__ U2sym) {
    int t = threadIdx.x;
    if (t < NSPEC) cnt[t] = 0;
    for (int task = t; task < 2640 + 360; task += blockDim.x) {
        if (task < 2640) {               // cubic: og(4) * m(165) * k(4)
            int og = task / 660;
            int r  = task - og * 660;
            int m  = r >> 2, k = r & 3;
            int a = 0, b = 0, d = 0;
            {   int idx = 0;
                for (int a0 = 0; a0 < 9; a0++)
                    for (int b0 = a0; b0 < 9; b0++)
                        for (int d0 = b0; d0 < 9; d0++) {
                            if (idx == m) { a = a0; b = b0; d = d0; }
                            idx++;
                        }
            }
            const float* U3 = (og == 0) ? U3_0e : U3_1o;
            int o = (og == 0) ? 0 : og - 1;
            const float* Ub = U3 + (size_t)o * 2916;   // [p][q][i][k] strides 324/36/4/1
            #define U3AT(p,q,i) Ub[((p)*9+(q))*36 + (i)*4 + k]
            float sum = U3AT(a,b,d) + U3AT(a,d,b) + U3AT(b,a,d)
                      + U3AT(b,d,a) + U3AT(d,a,b) + U3AT(d,b,a);
            #undef U3AT
            float sc = (a == b && b == d) ? (1.f/6.f)
                     : ((a == b || b == d || a == d) ? 0.5f : 1.f);
            U3sym[(og * 165 + m) * 4 + k] = sum * sc;
        } else {                          // quad: og(4) * q(45) * k(2)
            int t2 = task - 2640;
            int og = t2 / 90;
            int r  = t2 - og * 90;
            int q  = r >> 1, k = r & 1;
            int a = 0, b = 0;
            {   int idx = 0;
                for (int a0 = 0; a0 < 9; a0++)
                    for (int b0 = a0; b0 < 9; b0++) { if (idx == q) { a = a0; b = b0; } idx++; }
            }
            const float* U2 = (og == 0) ? U2_0e : U2_1o;
            int o = (og == 0) ? 0 : og - 1;
            const float* Ub = U2 + (size_t)o * 162;    // [p][i][k] strides 18/2/1
            float sum = Ub[(a*9 + b)*2 + k] + Ub[(b*9 + a)*2 + k];
            if (a == b) sum *= 0.5f;
            U2sym[(og * 45 + q) * 2 + k] = sum;
        }
    }
}

// ---------------------------------------------------------------------------
// Kernel 2: bucket node indices by species.
// ---------------------------------------------------------------------------
__global__ void k_lists(const int* __restrict__ specie, int* __restrict__ cnt,
                        int* __restrict__ list) {
    int i = blockIdx.x * blockDim.x + threadIdx.x;
    if (i < N_NODES) {
        int s = specie[i];
        int pos = atomicAdd(&cnt[s], 1);
        list[s * N_NODES + pos] = i;
    }
}

// ---------------------------------------------------------------------------
// Kernel 3: per-(s,c) monomial coefficients: contract Usym with W3/W2/W1.
// coeff layout: [s*128+c][mono 0..218][og 0..3]  (float4 per monomial)
// ---------------------------------------------------------------------------
__global__ void k_coeff(const float* __restrict__ U3sym, const float* __restrict__ U2sym,
                        const float* __restrict__ U1_0e, const float* __restrict__ U1_1o,
                        const float* __restrict__ W3_0e, const float* __restrict__ W3_1o,
                        const float* __restrict__ W2_0e, const float* __restrict__ W2_1o,
                        const float* __restrict__ W1_0e, const float* __restrict__ W1_1o,
                        float* __restrict__ coeff) {
    int blk = blockIdx.x;            // s*128 + c
    int s = blk >> 7, c = blk & 127;
    int t = threadIdx.x;
    if (t >= NMONO * 4) return;
    int m = t >> 2, og = t & 3;
    float val;
    if (m < NCUB) {
        const float* W3 = (og == 0) ? W3_0e : W3_1o;   // [s][k][c] strides 512/128/1
        const float* u  = U3sym + (og * 165 + m) * 4;
        val = u[0] * W3[s*512 +       c] + u[1] * W3[s*512 + 128 + c]
            + u[2] * W3[s*512 + 256 + c] + u[3] * W3[s*512 + 384 + c];
    } else if (m < NCUB + NQUAD) {
        int q = m - NCUB;
        const float* W2 = (og == 0) ? W2_0e : W2_1o;   // [s][k][c] strides 256/128/1
        const float* u  = U2sym + (og * 45 + q) * 2;
        val = u[0] * W2[s*256 + c] + u[1] * W2[s*256 + 128 + c];
    } else {
        int l = m - (NCUB + NQUAD);
        const float* U1 = (og == 0) ? U1_0e : U1_1o;   // [o][i][k=1]
        const float* W1 = (og == 0) ? W1_0e : W1_1o;   // [s][1][c]
        int o = (og == 0) ? 0 : og - 1;
        val = U1[o * 9 + l] * W1[s * 128 + c];
    }
    coeff[(size_t)blk * (NMONO * 4) + t] = val;
}

// ---------------------------------------------------------------------------
// Kernel 4: main contraction. Block = (s,c). Round-0 memory pattern (scattered
// per-lane 36B x reads: high MLP, L3-resident) + NEW: coefficient block staged
// in LDS once per block. Inner loop reads coeffs via ds_read_b128 at
// wave-uniform addresses (broadcast, conflict-free) -> deep lgkmcnt pipelining
// instead of the 219-deep s_load stall chain.
// f output: [n][c][og0..3] as float4.
// ---------------------------------------------------------------------------
__global__ __launch_bounds__(256) void k_main(const float* __restrict__ x,
        const int* __restrict__ cnt, const int* __restrict__ list,
        const float* __restrict__ coeff, float* __restrict__ fout) {
    __shared__ float cfs[NMONO * 4];         // 3504 B
    int blk = blockIdx.x;
    int s = blk >> 7, c = blk & 127;
    int n = cnt[s];
    {   // stage coefficients: 219 float4s, coalesced
        const float4* __restrict__ src = (const float4*)(coeff + (size_t)blk * (NMONO * 4));
        float4* dst = (float4*)cfs;
        for (int i = threadIdx.x; i < NMONO; i += 256) dst[i] = src[i];
    }
    __syncthreads();
    if (n == 0) return;
    const int* __restrict__ lst = list + s * N_NODES;

    for (int base = 0; base < n; base += 512) {
        int i0 = base + (int)threadIdx.x;
        int i1 = i0 + 256;
        int b0 = lst[i0 < n ? i0 : 0];
        int b1 = lst[i1 < n ? i1 : 0];
        const float* xp0 = x + ((size_t)b0 * C_CH + c) * 9;
        const float* xp1 = x + ((size_t)b1 * C_CH + c) * 9;
        float x0[9], x1[9];
        #pragma unroll
        for (int i = 0; i < 9; i++) { x0[i] = xp0[i]; x1[i] = xp1[i]; }

        float a0[4] = {0.f, 0.f, 0.f, 0.f};
        float a1[4] = {0.f, 0.f, 0.f, 0.f};
        int m3 = 0, m2 = 0;
        #pragma unroll
        for (int a = 0; a < 9; a++) {
            {   // linear term
                const float* cl = cfs + (210 + a) * 4;
                #pragma unroll
                for (int e = 0; e < 4; e++) { a0[e] = fmaf(cl[e], x0[a], a0[e]);
                                              a1[e] = fmaf(cl[e], x1[a], a1[e]); }
            }
            #pragma unroll
            for (int b = a; b < 9; b++) {
                float p0 = x0[a] * x0[b], p1 = x1[a] * x1[b];
                const float* cq = cfs + (165 + m2) * 4; m2++;
                #pragma unroll
                for (int e = 0; e < 4; e++) { a0[e] = fmaf(cq[e], p0, a0[e]);
                                              a1[e] = fmaf(cq[e], p1, a1[e]); }
                #pragma unroll
                for (int d = b; d < 9; d++) {
                    const float* c3 = cfs + m3 * 4; m3++;
                    float q0 = p0 * x0[d], q1 = p1 * x1[d];
                    #pragma unroll
                    for (int e = 0; e < 4; e++) { a0[e] = fmaf(c3[e], q0, a0[e]);
                                                  a1[e] = fmaf(c3[e], q1, a1[e]); }
                }
            }
        }
        if (i0 < n) *(float4*)&fout[((size_t)b0 * C_CH + c) * 4] = make_float4(a0[0], a0[1], a0[2], a0[3]);
        if (i1 < n) *(float4*)&fout[((size_t)b1 * C_CH + c) * 4] = make_float4(a1[0], a1[1], a1[2], a1[3]);
    }
}

// ---------------------------------------------------------------------------
// Kernel 5: epilogue linear (round-0 version). Block = (n-tile of 64, jg of 8);
// lane = node, wave owns 16 contiguous output channels.
// ---------------------------------------------------------------------------
__global__ __launch_bounds__(256) void k_epi(const float* __restrict__ f,
        const float* __restrict__ W0, const float* __restrict__ W1,
        const float* __restrict__ bias, float* __restrict__ out) {
    __shared__ float smem[128 * 65];        // ftile [c][n(64)+pad]; reused as trbuf [j][n]
    int bx = blockIdx.x;
    int ntile = bx >> 3, jg = bx & 7;       // 64 n-tiles x 8 j-groups of 64
    int n0 = ntile * 64;
    int t  = threadIdx.x;
    int o  = jg >> 1;                        // output component 0..3 (uniform per block)

    // stage f[., ., o] tile: 64 n x 128 c -> smem[c][n]
    #pragma unroll
    for (int r = 0; r < 32; ++r) {
        int flat = r * 256 + t;              // 8192 = 64n * 128c
        int n = flat >> 7, c = flat & 127;
        smem[c * 65 + n] = f[(size_t)(n0 + n) * 512 + c * 4 + o];
    }
    __syncthreads();

    int w    = __builtin_amdgcn_readfirstlane((int)(t >> 6));
    int lane = t & 63;
    int mb   = (jg & 1) * 64 + w * 16;       // wave's m base (uniform)
    const float* __restrict__ Wsel = (o == 0) ? W0 : W1;

    float acc[16];
    #pragma unroll
    for (int jj = 0; jj < 16; jj++) acc[jj] = 0.f;

    #pragma unroll 4
    for (int c = 0; c < 128; ++c) {
        float fv = smem[c * 65 + lane];
        #pragma unroll
        for (int jj = 0; jj < 16; jj++)
            acc[jj] = fmaf(fv, Wsel[c * 128 + mb + jj], acc[jj]);
    }
    __syncthreads();                          // all waves done reading ftile

    const float scale = 0.08838834764831845f; // 1/sqrt(128)
    #pragma unroll
    for (int jj = 0; jj < 16; jj++) {
        float v = acc[jj] * scale;
        if (o == 0) v += bias[mb + jj];
        smem[(w * 16 + jj) * 65 + lane] = v;  // trbuf[j_local][n]
    }
    __syncthreads();

    #pragma unroll
    for (int r = 0; r < 16; ++r) {
        int flat = r * 256 + t;               // 4096 = 64j * 64n
        int jl = flat & 63, n = flat >> 6;
        int m  = (jg & 1) * 64 + jl;
        int col = (o == 0) ? m : (128 + m * 3 + (o - 1));
        out[(size_t)(n0 + n) * 512 + col] = smem[jl * 65 + n];
    }
}

extern "C" void kernel_launch(void* const* d_in, const int* in_sizes, int n_in,
                              void* d_out, int out_size, void* d_ws, size_t ws_size,
                              hipStream_t stream) {
    const float* x     = (const float*)d_in[0];
    const int*   spec  = (const int*)  d_in[1];
    const float* U3_0e = (const float*)d_in[2];
    const float* U2_0e = (const float*)d_in[3];
    const float* U1_0e = (const float*)d_in[4];
    const float* W3_0e = (const float*)d_in[5];
    const float* W2_0e = (const float*)d_in[6];
    const float* W1_0e = (const float*)d_in[7];
    const float* U3_1o = (const float*)d_in[8];
    const float* U2_1o = (const float*)d_in[9];
    const float* U1_1o = (const float*)d_in[10];
    const float* W3_1o = (const float*)d_in[11];
    const float* W2_1o = (const float*)d_in[12];
    const float* W1_1o = (const float*)d_in[13];
    const float* Wlin0 = (const float*)d_in[14];
    const float* Wlin1 = (const float*)d_in[15];
    const float* bias0 = (const float*)d_in[16];
    float* out = (float*)d_out;

    char* ws = (char*)d_ws;
    int*   cnt   = (int*)  (ws + WS_CNT);
    int*   list  = (int*)  (ws + WS_LIST);
    float* U3sym = (float*)(ws + WS_U3SYM);
    float* U2sym = (float*)(ws + WS_U2SYM);
    float* coeff = (float*)(ws + WS_COEFF);
    float* f     = (float*)(ws + WS_F);
    (void)in_sizes; (void)n_in; (void)out_size; (void)ws_size;

    hipLaunchKernelGGL(k_prep,  dim3(1),    dim3(1024), 0, stream,
                       U3_0e, U3_1o, U2_0e, U2_1o, cnt, U3sym, U2sym);
    hipLaunchKernelGGL(k_lists, dim3(16),   dim3(256),  0, stream, spec, cnt, list);
    hipLaunchKernelGGL(k_coeff, dim3(1280), dim3(896),  0, stream,
                       U3sym, U2sym, U1_0e, U1_1o, W3_0e, W3_1o,
                       W2_0e, W2_1o, W1_0e, W1_1o, coeff);
    hipLaunchKernelGGL(k_main,  dim3(1280), dim3(256),  0, stream, x, cnt, list, coeff, f);
    hipLaunchKernelGGL(k_epi,   dim3(512),  dim3(256),  0, stream, f, Wlin0, Wlin1, bias0, out);
}

// Round 3
// 589.972 us; speedup vs baseline: 1.0142x; 1.0142x over previous
//
#include <hip/hip_runtime.h>

#define N_NODES 4096
#define C_CH    128
#define NSPEC   10
#define NCUB    165
#define NQUAD   45
#define NMONO   219   // 165 cubic + 45 quad + 9 linear

// ---- workspace layout (bytes); total ~12.5 MB ----
#define WS_CNT    0          // 10 ints
#define WS_OFF    64         // 11 ints
#define WS_LIST   128        // 10*4096 ints = 163840 -> 163968
#define WS_GMAP   163968     // 4096 ints -> 180352
#define WS_U3SYM  180352     // 10560 -> 190912
#define WS_U2SYM  190912     // 1440 -> 192352
#define WS_COEFF  192352     // 10s*219m*128c*4e floats = 4485120 -> 4677472 (16B aligned)
#define WS_F      4677472    // 4096*128*4 floats = 8388608 -> 13066080

// ---------------------------------------------------------------------------
// Kernel 1: zero species counters + build permutation-symmetrized U3/U2.
// ---------------------------------------------------------------------------
__global__ void k_prep(const float* __restrict__ U3_0e, const float* __restrict__ U3_1o,
                       const float* __restrict__ U2_0e, const float* __restrict__ U2_1o,
                       int* __restrict__ cnt, float* __restrict__ U3sym,
                       float* __restrict__ U2sym) {
    int t = threadIdx.x;
    if (t < NSPEC) cnt[t] = 0;
    for (int task = t; task < 2640 + 360; task += blockDim.x) {
        if (task < 2640) {               // cubic: og(4) * m(165) * k(4)
            int og = task / 660;
            int r  = task - og * 660;
            int m  = r >> 2, k = r & 3;
            int a = 0, b = 0, d = 0;
            {   int idx = 0;
                for (int a0 = 0; a0 < 9; a0++)
                    for (int b0 = a0; b0 < 9; b0++)
                        for (int d0 = b0; d0 < 9; d0++) {
                            if (idx == m) { a = a0; b = b0; d = d0; }
                            idx++;
                        }
            }
            const float* U3 = (og == 0) ? U3_0e : U3_1o;
            int o = (og == 0) ? 0 : og - 1;
            const float* Ub = U3 + (size_t)o * 2916;   // [p][q][i][k] strides 324/36/4/1
            #define U3AT(p,q,i) Ub[((p)*9+(q))*36 + (i)*4 + k]
            float sum = U3AT(a,b,d) + U3AT(a,d,b) + U3AT(b,a,d)
                      + U3AT(b,d,a) + U3AT(d,a,b) + U3AT(d,b,a);
            #undef U3AT
            float sc = (a == b && b == d) ? (1.f/6.f)
                     : ((a == b || b == d || a == d) ? 0.5f : 1.f);
            U3sym[(og * 165 + m) * 4 + k] = sum * sc;
        } else {                          // quad: og(4) * q(45) * k(2)
            int t2 = task - 2640;
            int og = t2 / 90;
            int r  = t2 - og * 90;
            int q  = r >> 1, k = r & 1;
            int a = 0, b = 0;
            {   int idx = 0;
                for (int a0 = 0; a0 < 9; a0++)
                    for (int b0 = a0; b0 < 9; b0++) { if (idx == q) { a = a0; b = b0; } idx++; }
            }
            const float* U2 = (og == 0) ? U2_0e : U2_1o;
            int o = (og == 0) ? 0 : og - 1;
            const float* Ub = U2 + (size_t)o * 162;    // [p][i][k] strides 18/2/1
            float sum = Ub[(a*9 + b)*2 + k] + Ub[(b*9 + a)*2 + k];
            if (a == b) sum *= 0.5f;
            U2sym[(og * 45 + q) * 2 + k] = sum;
        }
    }
}

// ---------------------------------------------------------------------------
// Kernel 2: bucket node indices by species.
// ---------------------------------------------------------------------------
__global__ void k_lists(const int* __restrict__ specie, int* __restrict__ cnt,
                        int* __restrict__ list) {
    int i = blockIdx.x * blockDim.x + threadIdx.x;
    if (i < N_NODES) {
        int s = specie[i];
        int pos = atomicAdd(&cnt[s], 1);
        list[s * N_NODES + pos] = i;
    }
}

// ---------------------------------------------------------------------------
// Kernel 2b: prefix-sum counts -> off[0..10]; flatten buckets -> gmap.
// ---------------------------------------------------------------------------
__global__ void k_off(const int* __restrict__ cnt, const int* __restrict__ list,
                      int* __restrict__ off, int* __restrict__ gmap) {
    __shared__ int soff[NSPEC + 1];
    int t = threadIdx.x;
    if (t == 0) {
        int acc = 0;
        for (int s = 0; s < NSPEC; s++) { soff[s] = acc; off[s] = acc; acc += cnt[s]; }
        soff[NSPEC] = acc; off[NSPEC] = acc;
    }
    __syncthreads();
    for (int s = 0; s < NSPEC; s++) {
        int n = soff[s + 1] - soff[s];
        for (int j = t; j < n; j += blockDim.x)
            gmap[soff[s] + j] = list[s * N_NODES + j];
    }
}

// ---------------------------------------------------------------------------
// Kernel 3: per-(s,c) monomial coefficients. NEW layout for vector streaming:
// coeff[s][m][c][e]  (lane c reads its float4 of monomial m coalesced).
// ---------------------------------------------------------------------------
__global__ void k_coeff(const float* __restrict__ U3sym, const float* __restrict__ U2sym,
                        const float* __restrict__ U1_0e, const float* __restrict__ U1_1o,
                        const float* __restrict__ W3_0e, const float* __restrict__ W3_1o,
                        const float* __restrict__ W2_0e, const float* __restrict__ W2_1o,
                        const float* __restrict__ W1_0e, const float* __restrict__ W1_1o,
                        float* __restrict__ coeff) {
    int blk = blockIdx.x;            // s*128 + c
    int s = blk >> 7, c = blk & 127;
    int t = threadIdx.x;
    if (t >= NMONO * 4) return;
    int m = t >> 2, og = t & 3;
    float val;
    if (m < NCUB) {
        const float* W3 = (og == 0) ? W3_0e : W3_1o;   // [s][k][c] strides 512/128/1
        const float* u  = U3sym + (og * 165 + m) * 4;
        val = u[0] * W3[s*512 +       c] + u[1] * W3[s*512 + 128 + c]
            + u[2] * W3[s*512 + 256 + c] + u[3] * W3[s*512 + 384 + c];
    } else if (m < NCUB + NQUAD) {
        int q = m - NCUB;
        const float* W2 = (og == 0) ? W2_0e : W2_1o;   // [s][k][c] strides 256/128/1
        const float* u  = U2sym + (og * 45 + q) * 2;
        val = u[0] * W2[s*256 + c] + u[1] * W2[s*256 + 128 + c];
    } else {
        int l = m - (NCUB + NQUAD);
        const float* U1 = (og == 0) ? U1_0e : U1_1o;   // [o][i][k=1]
        const float* W1 = (og == 0) ? W1_0e : W1_1o;   // [s][1][c]
        int o = (og == 0) ? 0 : og - 1;
        val = U1[o * 9 + l] * W1[s * 128 + c];
    }
    coeff[(((size_t)s * NMONO + m) * C_CH + c) * 4 + og] = val;
}

// ---------------------------------------------------------------------------
// Kernel 4: main contraction, channel-major waves (GEMM-style).
// Wave unit = (species, c-half, batch of 4 nodes). lane = channel.
// Coefficients stream as coalesced global_load_dwordx4 (vector pipe, vmcnt-
// pipelined, no s_load chain, no LICM-hoistable LDS). Each coeff load feeds
// 16 FMAs (4 nodes x 4 outputs). x: per node, lanes read a contiguous 2.3KB
// span (36B/lane) -- fully consumed. f out: [n][c][e] float4/lane, coalesced.
// ---------------------------------------------------------------------------
__global__ __launch_bounds__(256) void k_main(const float* __restrict__ x,
        const int* __restrict__ off, const int* __restrict__ gmap,
        const float* __restrict__ coeff, float* __restrict__ fout) {
    int wid  = blockIdx.x * 4 + ((int)threadIdx.x >> 6);
    int lane = (int)threadIdx.x & 63;

    // wave-uniform: map wid -> (species s, c-half ch, node-batch)
    int rem = wid, s = 0, n = 0;
    #pragma unroll 1
    for (; s < NSPEC; ++s) {
        n = off[s + 1] - off[s];
        int u = ((n + 3) >> 2) * 2;      // ceil(n/4) batches * 2 c-halves
        if (rem < u) break;
        rem -= u;
    }
    if (s >= NSPEC) return;
    int ch = rem & 1, batch = rem >> 1;
    int gb = off[s];
    int c  = ch * 64 + lane;
    int base = batch * 4;

    int  node[4];
    bool vld[4];
    #pragma unroll
    for (int j = 0; j < 4; ++j) {
        int k = base + j;
        vld[j]  = (k < n);
        node[j] = gmap[gb + (vld[j] ? k : 0)];
    }

    float xr[4][9];
    #pragma unroll
    for (int j = 0; j < 4; ++j) {
        const float* xp = x + ((size_t)node[j] * C_CH + c) * 9;
        #pragma unroll
        for (int i = 0; i < 9; ++i) xr[j][i] = xp[i];
    }

    const float4* __restrict__ cf4 =
        (const float4*)coeff + (size_t)s * (NMONO * C_CH) + c;   // stride C_CH per m

    float4 acc[4];
    #pragma unroll
    for (int j = 0; j < 4; ++j) acc[j] = make_float4(0.f, 0.f, 0.f, 0.f);

    int m3 = 0, m2 = 0;
    #pragma unroll
    for (int a = 0; a < 9; ++a) {
        {   // linear term
            float4 cl = cf4[(size_t)(210 + a) * C_CH];
            #pragma unroll
            for (int j = 0; j < 4; ++j) {
                acc[j].x = fmaf(cl.x, xr[j][a], acc[j].x);
                acc[j].y = fmaf(cl.y, xr[j][a], acc[j].y);
                acc[j].z = fmaf(cl.z, xr[j][a], acc[j].z);
                acc[j].w = fmaf(cl.w, xr[j][a], acc[j].w);
            }
        }
        #pragma unroll
        for (int b = a; b < 9; ++b) {
            float4 cq = cf4[(size_t)(165 + m2) * C_CH]; m2++;
            float p[4];
            #pragma unroll
            for (int j = 0; j < 4; ++j) {
                p[j] = xr[j][a] * xr[j][b];
                acc[j].x = fmaf(cq.x, p[j], acc[j].x);
                acc[j].y = fmaf(cq.y, p[j], acc[j].y);
                acc[j].z = fmaf(cq.z, p[j], acc[j].z);
                acc[j].w = fmaf(cq.w, p[j], acc[j].w);
            }
            #pragma unroll
            for (int d = b; d < 9; ++d) {
                float4 c3 = cf4[(size_t)m3 * C_CH]; m3++;
                #pragma unroll
                for (int j = 0; j < 4; ++j) {
                    float q = p[j] * xr[j][d];
                    acc[j].x = fmaf(c3.x, q, acc[j].x);
                    acc[j].y = fmaf(c3.y, q, acc[j].y);
                    acc[j].z = fmaf(c3.z, q, acc[j].z);
                    acc[j].w = fmaf(c3.w, q, acc[j].w);
                }
            }
        }
    }
    #pragma unroll
    for (int j = 0; j < 4; ++j)
        if (vld[j])
            *(float4*)&fout[((size_t)node[j] * C_CH + c) * 4] = acc[j];
}

// ---------------------------------------------------------------------------
// Kernel 5: epilogue linear (round-0 version, unchanged).
// ---------------------------------------------------------------------------
__global__ __launch_bounds__(256) void k_epi(const float* __restrict__ f,
        const float* __restrict__ W0, const float* __restrict__ W1,
        const float* __restrict__ bias, float* __restrict__ out) {
    __shared__ float smem[128 * 65];
    int bx = blockIdx.x;
    int ntile = bx >> 3, jg = bx & 7;
    int n0 = ntile * 64;
    int t  = threadIdx.x;
    int o  = jg >> 1;

    #pragma unroll
    for (int r = 0; r < 32; ++r) {
        int flat = r * 256 + t;
        int n = flat >> 7, c = flat & 127;
        smem[c * 65 + n] = f[(size_t)(n0 + n) * 512 + c * 4 + o];
    }
    __syncthreads();

    int w    = __builtin_amdgcn_readfirstlane((int)(t >> 6));
    int lane = t & 63;
    int mb   = (jg & 1) * 64 + w * 16;
    const float* __restrict__ Wsel = (o == 0) ? W0 : W1;

    float acc[16];
    #pragma unroll
    for (int jj = 0; jj < 16; jj++) acc[jj] = 0.f;

    #pragma unroll 4
    for (int c = 0; c < 128; ++c) {
        float fv = smem[c * 65 + lane];
        #pragma unroll
        for (int jj = 0; jj < 16; jj++)
            acc[jj] = fmaf(fv, Wsel[c * 128 + mb + jj], acc[jj]);
    }
    __syncthreads();

    const float scale = 0.08838834764831845f; // 1/sqrt(128)
    #pragma unroll
    for (int jj = 0; jj < 16; jj++) {
        float v = acc[jj] * scale;
        if (o == 0) v += bias[mb + jj];
        smem[(w * 16 + jj) * 65 + lane] = v;
    }
    __syncthreads();

    #pragma unroll
    for (int r = 0; r < 16; ++r) {
        int flat = r * 256 + t;
        int jl = flat & 63, n = flat >> 6;
        int m  = (jg & 1) * 64 + jl;
        int col = (o == 0) ? m : (128 + m * 3 + (o - 1));
        out[(size_t)(n0 + n) * 512 + col] = smem[jl * 65 + n];
    }
}

extern "C" void kernel_launch(void* const* d_in, const int* in_sizes, int n_in,
                              void* d_out, int out_size, void* d_ws, size_t ws_size,
                              hipStream_t stream) {
    const float* x     = (const float*)d_in[0];
    const int*   spec  = (const int*)  d_in[1];
    const float* U3_0e = (const float*)d_in[2];
    const float* U2_0e = (const float*)d_in[3];
    const float* U1_0e = (const float*)d_in[4];
    const float* W3_0e = (const float*)d_in[5];
    const float* W2_0e = (const float*)d_in[6];
    const float* W1_0e = (const float*)d_in[7];
    const float* U3_1o = (const float*)d_in[8];
    const float* U2_1o = (const float*)d_in[9];
    const float* U1_1o = (const float*)d_in[10];
    const float* W3_1o = (const float*)d_in[11];
    const float* W2_1o = (const float*)d_in[12];
    const float* W1_1o = (const float*)d_in[13];
    const float* Wlin0 = (const float*)d_in[14];
    const float* Wlin1 = (const float*)d_in[15];
    const float* bias0 = (const float*)d_in[16];
    float* out = (float*)d_out;

    char* ws = (char*)d_ws;
    int*   cnt   = (int*)  (ws + WS_CNT);
    int*   off   = (int*)  (ws + WS_OFF);
    int*   list  = (int*)  (ws + WS_LIST);
    int*   gmap  = (int*)  (ws + WS_GMAP);
    float* U3sym = (float*)(ws + WS_U3SYM);
    float* U2sym = (float*)(ws + WS_U2SYM);
    float* coeff = (float*)(ws + WS_COEFF);
    float* f     = (float*)(ws + WS_F);
    (void)in_sizes; (void)n_in; (void)out_size; (void)ws_size;

    hipLaunchKernelGGL(k_prep,  dim3(1),    dim3(1024), 0, stream,
                       U3_0e, U3_1o, U2_0e, U2_1o, cnt, U3sym, U2sym);
    hipLaunchKernelGGL(k_lists, dim3(16),   dim3(256),  0, stream, spec, cnt, list);
    hipLaunchKernelGGL(k_off,   dim3(1),    dim3(256),  0, stream, cnt, list, off, gmap);
    hipLaunchKernelGGL(k_coeff, dim3(1280), dim3(896),  0, stream,
                       U3sym, U2sym, U1_0e, U1_1o, W3_0e, W3_1o,
                       W2_0e, W2_1o, W1_0e, W1_1o, coeff);
    // max wave-units = sum_s 2*ceil(n_s/4) <= 2*(4096/4 + 10) = 2068 -> 520 blocks x 4 waves
    hipLaunchKernelGGL(k_main,  dim3(520),  dim3(256),  0, stream, x, off, gmap, coeff, f);
    hipLaunchKernelGGL(k_epi,   dim3(512),  dim3(256),  0, stream, f, Wlin0, Wlin1, bias0, out);
}

// Round 4
// 555.059 us; speedup vs baseline: 1.0780x; 1.0629x over previous
//
#include <hip/hip_runtime.h>

#define N_NODES 4096
#define C_CH    128
#define NSPEC   10
#define NCUB    165
#define NQUAD   45
#define NMONO   219   // 165 cubic + 45 quad + 9 linear
#define NBLK    1280  // (s,c) pairs
#define NTILE   8     // worst-case node tiles of 512 per (s,c)

// ---- workspace layout (bytes); total ~12.5 MB ----
#define WS_CNT    0            // 10 ints (species counts)
#define WS_LIST   256          // 10*4096 ints = 163840
#define WS_U3SYM  164096       // 4og*165*4k floats = 10560
#define WS_U2SYM  174656       // 4og*45*2k  floats = 1440
#define WS_COEFF  176096       // 1280*(219*4) floats = 4485120
#define WS_F      4661216      // 4096*128*4 floats  = 8388608

// ---------------------------------------------------------------------------
// Kernel 1: zero species counters + build permutation-symmetrized U3/U2.
// ---------------------------------------------------------------------------
__global__ void k_prep(const float* __restrict__ U3_0e, const float* __restrict__ U3_1o,
                       const float* __restrict__ U2_0e, const float* __restrict__ U2_1o,
                       int* __restrict__ cnt, float* __restrict__ U3sym,
                       float* __restrict__ U2sym) {
    int t = threadIdx.x;
    if (t < NSPEC) cnt[t] = 0;
    for (int task = t; task < 2640 + 360; task += blockDim.x) {
        if (task < 2640) {               // cubic: og(4) * m(165) * k(4)
            int og = task / 660;
            int r  = task - og * 660;
            int m  = r >> 2, k = r & 3;
            int a = 0, b = 0, d = 0;
            {   int idx = 0;
                for (int a0 = 0; a0 < 9; a0++)
                    for (int b0 = a0; b0 < 9; b0++)
                        for (int d0 = b0; d0 < 9; d0++) {
                            if (idx == m) { a = a0; b = b0; d = d0; }
                            idx++;
                        }
            }
            const float* U3 = (og == 0) ? U3_0e : U3_1o;
            int o = (og == 0) ? 0 : og - 1;
            const float* Ub = U3 + (size_t)o * 2916;   // [p][q][i][k] strides 324/36/4/1
            #define U3AT(p,q,i) Ub[((p)*9+(q))*36 + (i)*4 + k]
            float sum = U3AT(a,b,d) + U3AT(a,d,b) + U3AT(b,a,d)
                      + U3AT(b,d,a) + U3AT(d,a,b) + U3AT(d,b,a);
            #undef U3AT
            float sc = (a == b && b == d) ? (1.f/6.f)
                     : ((a == b || b == d || a == d) ? 0.5f : 1.f);
            U3sym[(og * 165 + m) * 4 + k] = sum * sc;
        } else {                          // quad: og(4) * q(45) * k(2)
            int t2 = task - 2640;
            int og = t2 / 90;
            int r  = t2 - og * 90;
            int q  = r >> 1, k = r & 1;
            int a = 0, b = 0;
            {   int idx = 0;
                for (int a0 = 0; a0 < 9; a0++)
                    for (int b0 = a0; b0 < 9; b0++) { if (idx == q) { a = a0; b = b0; } idx++; }
            }
            const float* U2 = (og == 0) ? U2_0e : U2_1o;
            int o = (og == 0) ? 0 : og - 1;
            const float* Ub = U2 + (size_t)o * 162;    // [p][i][k] strides 18/2/1
            float sum = Ub[(a*9 + b)*2 + k] + Ub[(b*9 + a)*2 + k];
            if (a == b) sum *= 0.5f;
            U2sym[(og * 45 + q) * 2 + k] = sum;
        }
    }
}

// ---------------------------------------------------------------------------
// Kernel 2: bucket node indices by species.
// ---------------------------------------------------------------------------
__global__ void k_lists(const int* __restrict__ specie, int* __restrict__ cnt,
                        int* __restrict__ list) {
    int i = blockIdx.x * blockDim.x + threadIdx.x;
    if (i < N_NODES) {
        int s = specie[i];
        int pos = atomicAdd(&cnt[s], 1);
        list[s * N_NODES + pos] = i;
    }
}

// ---------------------------------------------------------------------------
// Kernel 3: per-(s,c) monomial coefficients (round-0 layout):
// coeff[s*128+c][mono 0..218][og 0..3]  (float4 per monomial)
// ---------------------------------------------------------------------------
__global__ void k_coeff(const float* __restrict__ U3sym, const float* __restrict__ U2sym,
                        const float* __restrict__ U1_0e, const float* __restrict__ U1_1o,
                        const float* __restrict__ W3_0e, const float* __restrict__ W3_1o,
                        const float* __restrict__ W2_0e, const float* __restrict__ W2_1o,
                        const float* __restrict__ W1_0e, const float* __restrict__ W1_1o,
                        float* __restrict__ coeff) {
    int blk = blockIdx.x;            // s*128 + c
    int s = blk >> 7, c = blk & 127;
    int t = threadIdx.x;
    if (t >= NMONO * 4) return;
    int m = t >> 2, og = t & 3;
    float val;
    if (m < NCUB) {
        const float* W3 = (og == 0) ? W3_0e : W3_1o;   // [s][k][c] strides 512/128/1
        const float* u  = U3sym + (og * 165 + m) * 4;
        val = u[0] * W3[s*512 +       c] + u[1] * W3[s*512 + 128 + c]
            + u[2] * W3[s*512 + 256 + c] + u[3] * W3[s*512 + 384 + c];
    } else if (m < NCUB + NQUAD) {
        int q = m - NCUB;
        const float* W2 = (og == 0) ? W2_0e : W2_1o;   // [s][k][c] strides 256/128/1
        const float* u  = U2sym + (og * 45 + q) * 2;
        val = u[0] * W2[s*256 + c] + u[1] * W2[s*256 + 128 + c];
    } else {
        int l = m - (NCUB + NQUAD);
        const float* U1 = (og == 0) ? U1_0e : U1_1o;   // [o][i][k=1]
        const float* W1 = (og == 0) ? W1_0e : W1_1o;   // [s][1][c]
        int o = (og == 0) ? 0 : og - 1;
        val = U1[o * 9 + l] * W1[s * 128 + c];
    }
    coeff[(size_t)blk * (NMONO * 4) + t] = val;
}

// ---------------------------------------------------------------------------
// Kernel 4: main contraction.
// Block = (node-tile, s, c). NO outer loop (grid covers tiles) -> nothing for
// LICM to hoist across. Coeffs staged once to LDS (3.5 KB), read as float4 at
// wave-uniform addresses (broadcast, lgkmcnt-pipelined). Per-(a,b) monomial
// group fenced with sched_barrier(ALU|VALU may cross): ds_reads stay in their
// ~11-load group (bounded VGPR), FMAs free to schedule across groups.
// x reads: round-0 scattered per-lane 36B spans (high MLP). 2 nodes/thread.
// ---------------------------------------------------------------------------
__global__ __launch_bounds__(256) void k_main(const float* __restrict__ x,
        const int* __restrict__ cnt, const int* __restrict__ list,
        const float* __restrict__ coeff, float* __restrict__ fout) {
    __shared__ float cfs[NMONO * 4];         // 3504 B
    int bx   = blockIdx.x;
    int tile = bx / NBLK;
    int blk  = bx - tile * NBLK;
    int s = blk >> 7, c = blk & 127;
    int n = cnt[s];
    if (tile * 512 >= n) return;             // block-uniform exit (before sync)

    if (threadIdx.x < NMONO)
        ((float4*)cfs)[threadIdx.x] =
            ((const float4*)(coeff + (size_t)blk * (NMONO * 4)))[threadIdx.x];
    __syncthreads();

    const int* __restrict__ lst = list + s * N_NODES;
    int i0 = tile * 512 + (int)threadIdx.x;
    int i1 = i0 + 256;
    int b0 = lst[i0 < n ? i0 : 0];
    int b1 = lst[i1 < n ? i1 : 0];
    const float* xp0 = x + ((size_t)b0 * C_CH + c) * 9;
    const float* xp1 = x + ((size_t)b1 * C_CH + c) * 9;
    float x0[9], x1[9];
    #pragma unroll
    for (int i = 0; i < 9; i++) { x0[i] = xp0[i]; x1[i] = xp1[i]; }

    float a0[4] = {0.f, 0.f, 0.f, 0.f};
    float a1[4] = {0.f, 0.f, 0.f, 0.f};
    int m3 = 0, m2 = 0;
    #pragma unroll
    for (int a = 0; a < 9; a++) {
        {   // linear term
            float4 cl = *(const float4*)&cfs[(210 + a) * 4];
            a0[0] = fmaf(cl.x, x0[a], a0[0]);  a1[0] = fmaf(cl.x, x1[a], a1[0]);
            a0[1] = fmaf(cl.y, x0[a], a0[1]);  a1[1] = fmaf(cl.y, x1[a], a1[1]);
            a0[2] = fmaf(cl.z, x0[a], a0[2]);  a1[2] = fmaf(cl.z, x1[a], a1[2]);
            a0[3] = fmaf(cl.w, x0[a], a0[3]);  a1[3] = fmaf(cl.w, x1[a], a1[3]);
        }
        #pragma unroll
        for (int b = a; b < 9; b++) {
            float p0 = x0[a] * x0[b], p1 = x1[a] * x1[b];
            {
                float4 cq = *(const float4*)&cfs[(165 + m2) * 4]; m2++;
                a0[0] = fmaf(cq.x, p0, a0[0]);  a1[0] = fmaf(cq.x, p1, a1[0]);
                a0[1] = fmaf(cq.y, p0, a0[1]);  a1[1] = fmaf(cq.y, p1, a1[1]);
                a0[2] = fmaf(cq.z, p0, a0[2]);  a1[2] = fmaf(cq.z, p1, a1[2]);
                a0[3] = fmaf(cq.w, p0, a0[3]);  a1[3] = fmaf(cq.w, p1, a1[3]);
            }
            #pragma unroll
            for (int d = b; d < 9; d++) {
                float4 c3 = *(const float4*)&cfs[m3 * 4]; m3++;
                float q0 = p0 * x0[d], q1 = p1 * x1[d];
                a0[0] = fmaf(c3.x, q0, a0[0]);  a1[0] = fmaf(c3.x, q1, a1[0]);
                a0[1] = fmaf(c3.y, q0, a0[1]);  a1[1] = fmaf(c3.y, q1, a1[1]);
                a0[2] = fmaf(c3.z, q0, a0[2]);  a1[2] = fmaf(c3.z, q1, a1[2]);
                a0[3] = fmaf(c3.w, q0, a0[3]);  a1[3] = fmaf(c3.w, q1, a1[3]);
            }
            // fence: ds_reads may not cross (bounds in-flight LDS data / VGPR);
            // ALU(0x1)|VALU(0x2) may cross (FMA pipelining preserved).
            __builtin_amdgcn_sched_barrier(0x3);
        }
    }
    if (i0 < n) *(float4*)&fout[((size_t)b0 * C_CH + c) * 4] = make_float4(a0[0], a0[1], a0[2], a0[3]);
    if (i1 < n) *(float4*)&fout[((size_t)b1 * C_CH + c) * 4] = make_float4(a1[0], a1[1], a1[2], a1[3]);
}

// ---------------------------------------------------------------------------
// Kernel 5: epilogue linear (round-0 version, unchanged).
// ---------------------------------------------------------------------------
__global__ __launch_bounds__(256) void k_epi(const float* __restrict__ f,
        const float* __restrict__ W0, const float* __restrict__ W1,
        const float* __restrict__ bias, float* __restrict__ out) {
    __shared__ float smem[128 * 65];        // ftile [c][n(64)+pad]; reused as trbuf [j][n]
    int bx = blockIdx.x;
    int ntile = bx >> 3, jg = bx & 7;       // 64 n-tiles x 8 j-groups of 64
    int n0 = ntile * 64;
    int t  = threadIdx.x;
    int o  = jg >> 1;                        // output component 0..3 (uniform per block)

    #pragma unroll
    for (int r = 0; r < 32; ++r) {
        int flat = r * 256 + t;              // 8192 = 64n * 128c
        int n = flat >> 7, c = flat & 127;
        smem[c * 65 + n] = f[(size_t)(n0 + n) * 512 + c * 4 + o];
    }
    __syncthreads();

    int w    = __builtin_amdgcn_readfirstlane((int)(t >> 6));
    int lane = t & 63;
    int mb   = (jg & 1) * 64 + w * 16;       // wave's m base (uniform)
    const float* __restrict__ Wsel = (o == 0) ? W0 : W1;

    float acc[16];
    #pragma unroll
    for (int jj = 0; jj < 16; jj++) acc[jj] = 0.f;

    #pragma unroll 4
    for (int c = 0; c < 128; ++c) {
        float fv = smem[c * 65 + lane];
        #pragma unroll
        for (int jj = 0; jj < 16; jj++)
            acc[jj] = fmaf(fv, Wsel[c * 128 + mb + jj], acc[jj]);
    }
    __syncthreads();

    const float scale = 0.08838834764831845f; // 1/sqrt(128)
    #pragma unroll
    for (int jj = 0; jj < 16; jj++) {
        float v = acc[jj] * scale;
        if (o == 0) v += bias[mb + jj];
        smem[(w * 16 + jj) * 65 + lane] = v;  // trbuf[j_local][n]
    }
    __syncthreads();

    #pragma unroll
    for (int r = 0; r < 16; ++r) {
        int flat = r * 256 + t;               // 4096 = 64j * 64n
        int jl = flat & 63, n = flat >> 6;
        int m  = (jg & 1) * 64 + jl;
        int col = (o == 0) ? m : (128 + m * 3 + (o - 1));
        out[(size_t)(n0 + n) * 512 + col] = smem[jl * 65 + n];
    }
}

extern "C" void kernel_launch(void* const* d_in, const int* in_sizes, int n_in,
                              void* d_out, int out_size, void* d_ws, size_t ws_size,
                              hipStream_t stream) {
    const float* x     = (const float*)d_in[0];
    const int*   spec  = (const int*)  d_in[1];
    const float* U3_0e = (const float*)d_in[2];
    const float* U2_0e = (const float*)d_in[3];
    const float* U1_0e = (const float*)d_in[4];
    const float* W3_0e = (const float*)d_in[5];
    const float* W2_0e = (const float*)d_in[6];
    const float* W1_0e = (const float*)d_in[7];
    const float* U3_1o = (const float*)d_in[8];
    const float* U2_1o = (const float*)d_in[9];
    const float* U1_1o = (const float*)d_in[10];
    const float* W3_1o = (const float*)d_in[11];
    const float* W2_1o = (const float*)d_in[12];
    const float* W1_1o = (const float*)d_in[13];
    const float* Wlin0 = (const float*)d_in[14];
    const float* Wlin1 = (const float*)d_in[15];
    const float* bias0 = (const float*)d_in[16];
    float* out = (float*)d_out;

    char* ws = (char*)d_ws;
    int*   cnt   = (int*)  (ws + WS_CNT);
    int*   list  = (int*)  (ws + WS_LIST);
    float* U3sym = (float*)(ws + WS_U3SYM);
    float* U2sym = (float*)(ws + WS_U2SYM);
    float* coeff = (float*)(ws + WS_COEFF);
    float* f     = (float*)(ws + WS_F);
    (void)in_sizes; (void)n_in; (void)out_size; (void)ws_size;

    hipLaunchKernelGGL(k_prep,  dim3(1),    dim3(1024), 0, stream,
                       U3_0e, U3_1o, U2_0e, U2_1o, cnt, U3sym, U2sym);
    hipLaunchKernelGGL(k_lists, dim3(16),   dim3(256),  0, stream, spec, cnt, list);
    hipLaunchKernelGGL(k_coeff, dim3(1280), dim3(896),  0, stream,
                       U3sym, U2sym, U1_0e, U1_1o, W3_0e, W3_1o,
                       W2_0e, W2_1o, W1_0e, W1_1o, coeff);
    // grid covers (tile, s, c); tiles beyond ceil(n_s/512) exit immediately.
    hipLaunchKernelGGL(k_main,  dim3(NBLK * NTILE), dim3(256), 0, stream,
                       x, cnt, list, coeff, f);
    hipLaunchKernelGGL(k_epi,   dim3(512),  dim3(256),  0, stream, f, Wlin0, Wlin1, bias0, out);
}

// Round 5
// 185.195 us; speedup vs baseline: 3.2309x; 2.9972x over previous
//
#include <hip/hip_runtime.h>

#define N_NODES 4096
#define C_CH    128
#define NSPEC   10
#define NCUB    165
#define NQUAD   45
#define NMONO   219   // 165 cubic + 45 quad + 9 linear
#define NBLK    1280  // (s,c) pairs
#define NTILE   8     // worst-case node tiles of 512 per (s,c)

// ---- workspace layout (bytes); total ~12.5 MB ----
#define WS_CNT    0            // 10 ints (species counts)
#define WS_LIST   256          // 10*4096 ints = 163840
#define WS_U3SYM  164096       // 4og*165*4k floats = 10560
#define WS_U2SYM  174656       // 4og*45*2k  floats = 1440
#define WS_COEFF  176096       // 1280*(219*4) floats = 4485120
#define WS_F      4661216      // 4096*128*4 floats  = 8388608

// ---------------------------------------------------------------------------
// Kernel 1: zero species counters + build permutation-symmetrized U3/U2.
// (a,b,d)/(a,b) index decode done ONCE into LDS tables instead of a 729-scan
// per task.
// ---------------------------------------------------------------------------
__global__ void k_prep(const float* __restrict__ U3_0e, const float* __restrict__ U3_1o,
                       const float* __restrict__ U2_0e, const float* __restrict__ U2_1o,
                       int* __restrict__ cnt, float* __restrict__ U3sym,
                       float* __restrict__ U2sym) {
    __shared__ unsigned char ta[NCUB], tb[NCUB], td[NCUB], qa[NQUAD], qb[NQUAD];
    int t = threadIdx.x;
    if (t < NSPEC) cnt[t] = 0;
    if (t < NCUB) {
        int idx = 0, a = 0, b = 0, d = 0;
        for (int a0 = 0; a0 < 9; a0++)
            for (int b0 = a0; b0 < 9; b0++)
                for (int d0 = b0; d0 < 9; d0++) {
                    if (idx == t) { a = a0; b = b0; d = d0; }
                    idx++;
                }
        ta[t] = a; tb[t] = b; td[t] = d;
    } else if (t >= 256 && t < 256 + NQUAD) {
        int q = t - 256, idx = 0, a = 0, b = 0;
        for (int a0 = 0; a0 < 9; a0++)
            for (int b0 = a0; b0 < 9; b0++) { if (idx == q) { a = a0; b = b0; } idx++; }
        qa[q] = a; qb[q] = b;
    }
    __syncthreads();
    for (int task = t; task < 2640 + 360; task += blockDim.x) {
        if (task < 2640) {               // cubic: og(4) * m(165) * k(4)
            int og = task / 660;
            int r  = task - og * 660;
            int m  = r >> 2, k = r & 3;
            int a = ta[m], b = tb[m], d = td[m];
            const float* U3 = (og == 0) ? U3_0e : U3_1o;
            int o = (og == 0) ? 0 : og - 1;
            const float* Ub = U3 + (size_t)o * 2916;   // [p][q][i][k] strides 324/36/4/1
            #define U3AT(p,q,i) Ub[((p)*9+(q))*36 + (i)*4 + k]
            float sum = U3AT(a,b,d) + U3AT(a,d,b) + U3AT(b,a,d)
                      + U3AT(b,d,a) + U3AT(d,a,b) + U3AT(d,b,a);
            #undef U3AT
            float sc = (a == b && b == d) ? (1.f/6.f)
                     : ((a == b || b == d || a == d) ? 0.5f : 1.f);
            U3sym[(og * 165 + m) * 4 + k] = sum * sc;
        } else {                          // quad: og(4) * q(45) * k(2)
            int t2 = task - 2640;
            int og = t2 / 90;
            int r  = t2 - og * 90;
            int q  = r >> 1, k = r & 1;
            int a = qa[q], b = qb[q];
            const float* U2 = (og == 0) ? U2_0e : U2_1o;
            int o = (og == 0) ? 0 : og - 1;
            const float* Ub = U2 + (size_t)o * 162;    // [p][i][k] strides 18/2/1
            float sum = Ub[(a*9 + b)*2 + k] + Ub[(b*9 + a)*2 + k];
            if (a == b) sum *= 0.5f;
            U2sym[(og * 45 + q) * 2 + k] = sum;
        }
    }
}

// ---------------------------------------------------------------------------
// Kernel 2: bucket node indices by species.
// ---------------------------------------------------------------------------
__global__ void k_lists(const int* __restrict__ specie, int* __restrict__ cnt,
                        int* __restrict__ list) {
    int i = blockIdx.x * blockDim.x + threadIdx.x;
    if (i < N_NODES) {
        int s = specie[i];
        int pos = atomicAdd(&cnt[s], 1);
        list[s * N_NODES + pos] = i;
    }
}

// ---------------------------------------------------------------------------
// Kernel 3: per-(s,c) monomial coefficients (round-0 layout):
// coeff[s*128+c][mono 0..218][og 0..3]  (float4 per monomial)
// ---------------------------------------------------------------------------
__global__ void k_coeff(const float* __restrict__ U3sym, const float* __restrict__ U2sym,
                        const float* __restrict__ U1_0e, const float* __restrict__ U1_1o,
                        const float* __restrict__ W3_0e, const float* __restrict__ W3_1o,
                        const float* __restrict__ W2_0e, const float* __restrict__ W2_1o,
                        const float* __restrict__ W1_0e, const float* __restrict__ W1_1o,
                        float* __restrict__ coeff) {
    int blk = blockIdx.x;            // s*128 + c
    int s = blk >> 7, c = blk & 127;
    int t = threadIdx.x;
    if (t >= NMONO * 4) return;
    int m = t >> 2, og = t & 3;
    float val;
    if (m < NCUB) {
        const float* W3 = (og == 0) ? W3_0e : W3_1o;   // [s][k][c] strides 512/128/1
        const float* u  = U3sym + (og * 165 + m) * 4;
        val = u[0] * W3[s*512 +       c] + u[1] * W3[s*512 + 128 + c]
            + u[2] * W3[s*512 + 256 + c] + u[3] * W3[s*512 + 384 + c];
    } else if (m < NCUB + NQUAD) {
        int q = m - NCUB;
        const float* W2 = (og == 0) ? W2_0e : W2_1o;   // [s][k][c] strides 256/128/1
        const float* u  = U2sym + (og * 45 + q) * 2;
        val = u[0] * W2[s*256 + c] + u[1] * W2[s*256 + 128 + c];
    } else {
        int l = m - (NCUB + NQUAD);
        const float* U1 = (og == 0) ? U1_0e : U1_1o;   // [o][i][k=1]
        const float* W1 = (og == 0) ? W1_0e : W1_1o;   // [s][1][c]
        int o = (og == 0) ? 0 : og - 1;
        val = U1[o * 9 + l] * W1[s * 128 + c];
    }
    coeff[(size_t)blk * (NMONO * 4) + t] = val;
}

// ---------------------------------------------------------------------------
// Kernel 4: main contraction -- REAL LOOPS, no unroll, nothing to spill.
// Block = (node-tile, s, c). Per-thread x (2 nodes x 9) lives in LDS as
// float2[i][tid] (dynamic index legal in LDS; i-major -> b64 reads at the
// inherent 2-round minimum, no extra bank conflict). Coefficients staged once
// to LDS (3.5 KB), walked linearly with a loop-carried offset, read as
// wave-uniform broadcast ds_read_b128. Triangular (a,b,d) nest kept as real
// loops (#pragma unroll 1): live set ~40 VGPR, high occupancy, DS pipe hides
// under VALU. x global reads keep round-0 scattered pattern (high MLP).
// f output: [n][c][og0..3] as float4.
// ---------------------------------------------------------------------------
__global__ __launch_bounds__(256) void k_main(const float* __restrict__ x,
        const int* __restrict__ cnt, const int* __restrict__ list,
        const float* __restrict__ coeff, float* __restrict__ fout) {
    __shared__ float  cfs[NMONO * 4];        // 3504 B
    __shared__ float2 xsh[9 * 256];          // 18432 B, [i][tid]
    int bx   = blockIdx.x;
    int tile = bx / NBLK;
    int blk  = bx - tile * NBLK;
    int s = blk >> 7, c = blk & 127;
    int n = cnt[s];
    if (tile * 512 >= n) return;             // block-uniform exit (before sync)

    int tid = threadIdx.x;
    if (tid < NMONO)
        ((float4*)cfs)[tid] =
            ((const float4*)(coeff + (size_t)blk * (NMONO * 4)))[tid];

    const int* __restrict__ lst = list + s * N_NODES;
    int i0 = tile * 512 + tid;
    int i1 = i0 + 256;
    int b0 = lst[i0 < n ? i0 : 0];
    int b1 = lst[i1 < n ? i1 : 0];
    const float* xp0 = x + ((size_t)b0 * C_CH + c) * 9;
    const float* xp1 = x + ((size_t)b1 * C_CH + c) * 9;
    #pragma unroll
    for (int i = 0; i < 9; i++)
        xsh[i * 256 + tid] = make_float2(xp0[i], xp1[i]);
    __syncthreads();

    float a0[4] = {0.f, 0.f, 0.f, 0.f};
    float a1[4] = {0.f, 0.f, 0.f, 0.f};
    int mcub = 0, mquad = 0;

    #pragma unroll 1
    for (int a = 0; a < 9; a++) {
        float2 xa = xsh[a * 256 + tid];
        {   // linear term
            float4 cl = *(const float4*)&cfs[(210 + a) * 4];
            a0[0] = fmaf(cl.x, xa.x, a0[0]);  a1[0] = fmaf(cl.x, xa.y, a1[0]);
            a0[1] = fmaf(cl.y, xa.x, a0[1]);  a1[1] = fmaf(cl.y, xa.y, a1[1]);
            a0[2] = fmaf(cl.z, xa.x, a0[2]);  a1[2] = fmaf(cl.z, xa.y, a1[2]);
            a0[3] = fmaf(cl.w, xa.x, a0[3]);  a1[3] = fmaf(cl.w, xa.y, a1[3]);
        }
        #pragma unroll 1
        for (int b = a; b < 9; b++) {
            float2 xb = xsh[b * 256 + tid];
            float p0 = xa.x * xb.x, p1 = xa.y * xb.y;
            {
                float4 cq = *(const float4*)&cfs[(165 + mquad) * 4]; mquad++;
                a0[0] = fmaf(cq.x, p0, a0[0]);  a1[0] = fmaf(cq.x, p1, a1[0]);
                a0[1] = fmaf(cq.y, p0, a0[1]);  a1[1] = fmaf(cq.y, p1, a1[1]);
                a0[2] = fmaf(cq.z, p0, a0[2]);  a1[2] = fmaf(cq.z, p1, a1[2]);
                a0[3] = fmaf(cq.w, p0, a0[3]);  a1[3] = fmaf(cq.w, p1, a1[3]);
            }
            #pragma unroll 1
            for (int d = b; d < 9; d++) {
                float2 xd = xsh[d * 256 + tid];
                float4 c3 = *(const float4*)&cfs[mcub * 4]; mcub++;
                float q0 = p0 * xd.x, q1 = p1 * xd.y;
                a0[0] = fmaf(c3.x, q0, a0[0]);  a1[0] = fmaf(c3.x, q1, a1[0]);
                a0[1] = fmaf(c3.y, q0, a0[1]);  a1[1] = fmaf(c3.y, q1, a1[1]);
                a0[2] = fmaf(c3.z, q0, a0[2]);  a1[2] = fmaf(c3.z, q1, a1[2]);
                a0[3] = fmaf(c3.w, q0, a0[3]);  a1[3] = fmaf(c3.w, q1, a1[3]);
            }
        }
    }
    if (i0 < n) *(float4*)&fout[((size_t)b0 * C_CH + c) * 4] = make_float4(a0[0], a0[1], a0[2], a0[3]);
    if (i1 < n) *(float4*)&fout[((size_t)b1 * C_CH + c) * 4] = make_float4(a1[0], a1[1], a1[2], a1[3]);
}

// ---------------------------------------------------------------------------
// Kernel 5: epilogue linear (round-0 version, unchanged).
// ---------------------------------------------------------------------------
__global__ __launch_bounds__(256) void k_epi(const float* __restrict__ f,
        const float* __restrict__ W0, const float* __restrict__ W1,
        const float* __restrict__ bias, float* __restrict__ out) {
    __shared__ float smem[128 * 65];        // ftile [c][n(64)+pad]; reused as trbuf [j][n]
    int bx = blockIdx.x;
    int ntile = bx >> 3, jg = bx & 7;       // 64 n-tiles x 8 j-groups of 64
    int n0 = ntile * 64;
    int t  = threadIdx.x;
    int o  = jg >> 1;                        // output component 0..3 (uniform per block)

    #pragma unroll
    for (int r = 0; r < 32; ++r) {
        int flat = r * 256 + t;              // 8192 = 64n * 128c
        int n = flat >> 7, c = flat & 127;
        smem[c * 65 + n] = f[(size_t)(n0 + n) * 512 + c * 4 + o];
    }
    __syncthreads();

    int w    = __builtin_amdgcn_readfirstlane((int)(t >> 6));
    int lane = t & 63;
    int mb   = (jg & 1) * 64 + w * 16;       // wave's m base (uniform)
    const float* __restrict__ Wsel = (o == 0) ? W0 : W1;

    float acc[16];
    #pragma unroll
    for (int jj = 0; jj < 16; jj++) acc[jj] = 0.f;

    #pragma unroll 4
    for (int c = 0; c < 128; ++c) {
        float fv = smem[c * 65 + lane];
        #pragma unroll
        for (int jj = 0; jj < 16; jj++)
            acc[jj] = fmaf(fv, Wsel[c * 128 + mb + jj], acc[jj]);
    }
    __syncthreads();

    const float scale = 0.08838834764831845f; // 1/sqrt(128)
    #pragma unroll
    for (int jj = 0; jj < 16; jj++) {
        float v = acc[jj] * scale;
        if (o == 0) v += bias[mb + jj];
        smem[(w * 16 + jj) * 65 + lane] = v;  // trbuf[j_local][n]
    }
    __syncthreads();

    #pragma unroll
    for (int r = 0; r < 16; ++r) {
        int flat = r * 256 + t;               // 4096 = 64j * 64n
        int jl = flat & 63, n = flat >> 6;
        int m  = (jg & 1) * 64 + jl;
        int col = (o == 0) ? m : (128 + m * 3 + (o - 1));
        out[(size_t)(n0 + n) * 512 + col] = smem[jl * 65 + n];
    }
}

extern "C" void kernel_launch(void* const* d_in, const int* in_sizes, int n_in,
                              void* d_out, int out_size, void* d_ws, size_t ws_size,
                              hipStream_t stream) {
    const float* x     = (const float*)d_in[0];
    const int*   spec  = (const int*)  d_in[1];
    const float* U3_0e = (const float*)d_in[2];
    const float* U2_0e = (const float*)d_in[3];
    const float* U1_0e = (const float*)d_in[4];
    const float* W3_0e = (const float*)d_in[5];
    const float* W2_0e = (const float*)d_in[6];
    const float* W1_0e = (const float*)d_in[7];
    const float* U3_1o = (const float*)d_in[8];
    const float* U2_1o = (const float*)d_in[9];
    const float* U1_1o = (const float*)d_in[10];
    const float* W3_1o = (const float*)d_in[11];
    const float* W2_1o = (const float*)d_in[12];
    const float* W1_1o = (const float*)d_in[13];
    const float* Wlin0 = (const float*)d_in[14];
    const float* Wlin1 = (const float*)d_in[15];
    const float* bias0 = (const float*)d_in[16];
    float* out = (float*)d_out;

    char* ws = (char*)d_ws;
    int*   cnt   = (int*)  (ws + WS_CNT);
    int*   list  = (int*)  (ws + WS_LIST);
    float* U3sym = (float*)(ws + WS_U3SYM);
    float* U2sym = (float*)(ws + WS_U2SYM);
    float* coeff = (float*)(ws + WS_COEFF);
    float* f     = (float*)(ws + WS_F);
    (void)in_sizes; (void)n_in; (void)out_size; (void)ws_size;

    hipLaunchKernelGGL(k_prep,  dim3(1),    dim3(1024), 0, stream,
                       U3_0e, U3_1o, U2_0e, U2_1o, cnt, U3sym, U2sym);
    hipLaunchKernelGGL(k_lists, dim3(16),   dim3(256),  0, stream, spec, cnt, list);
    hipLaunchKernelGGL(k_coeff, dim3(1280), dim3(896),  0, stream,
                       U3sym, U2sym, U1_0e, U1_1o, W3_0e, W3_1o,
                       W2_0e, W2_1o, W1_0e, W1_1o, coeff);
    // grid covers (tile, s, c); tiles beyond ceil(n_s/512) exit immediately.
    hipLaunchKernelGGL(k_main,  dim3(NBLK * NTILE), dim3(256), 0, stream,
                       x, cnt, list, coeff, f);
    hipLaunchKernelGGL(k_epi,   dim3(512),  dim3(256),  0, stream, f, Wlin0, Wlin1, bias0, out);
}

// Round 6
// 165.226 us; speedup vs baseline: 3.6213x; 1.1209x over previous
//
#include <hip/hip_runtime.h>

#define N_NODES 4096
#define C_CH    128
#define NSPEC   10
#define NCUB    165
#define NQUAD   45
#define NMONO   219   // 165 cubic + 45 quad + 9 linear
#define NBLK    1280  // (s,c) pairs
#define NTILE   8     // worst-case node tiles of 512 per (s,c)

// ---- workspace layout (bytes); total ~8.2 MB ----
#define WS_CNT    0            // 10 ints (species counts)
#define WS_LIST   256          // 10*4096 ints = 163840
#define WS_U3SYM  164096       // 4og*165*4k floats = 10560
#define WS_U2SYM  174656       // 4og*45*2k  floats = 1440
#define WS_F      176096       // 4096*128*4 floats  = 8388608

// ---------------------------------------------------------------------------
// Kernel 1 (fused): blocks 0..7 build permutation-symmetrized U3/U2 (parallel
// across 8 blocks -- the old single-block version serialized cold U3 loads on
// one CU). Block 8 buckets nodes by species using LDS-local counters (no
// pre-zeroed global cnt needed), then publishes cnt.
// ---------------------------------------------------------------------------
__global__ __launch_bounds__(256) void k_prep(
        const float* __restrict__ U3_0e, const float* __restrict__ U3_1o,
        const float* __restrict__ U2_0e, const float* __restrict__ U2_1o,
        const int* __restrict__ specie, int* __restrict__ cnt,
        int* __restrict__ list, float* __restrict__ U3sym,
        float* __restrict__ U2sym) {
    int blk = blockIdx.x;
    int t   = threadIdx.x;

    if (blk == 8) {   // ---- lists part (single block, LDS counters) ----
        __shared__ int scnt[NSPEC];
        if (t < NSPEC) scnt[t] = 0;
        __syncthreads();
        for (int i = t; i < N_NODES; i += 256) {
            int s = specie[i];
            int pos = atomicAdd(&scnt[s], 1);
            list[s * N_NODES + pos] = i;
        }
        __syncthreads();
        if (t < NSPEC) cnt[t] = scnt[t];
        return;
    }

    // ---- prep part: blocks 0..7 ----
    __shared__ unsigned char ta[NCUB], tb[NCUB], td[NCUB], qa[NQUAD], qb[NQUAD];
    if (t < NCUB) {
        int idx = 0, a = 0, b = 0, d = 0;
        for (int a0 = 0; a0 < 9; a0++)
            for (int b0 = a0; b0 < 9; b0++)
                for (int d0 = b0; d0 < 9; d0++) {
                    if (idx == t) { a = a0; b = b0; d = d0; }
                    idx++;
                }
        ta[t] = a; tb[t] = b; td[t] = d;
    } else if (t >= NCUB && t < NCUB + NQUAD) {
        int q = t - NCUB, idx = 0, a = 0, b = 0;
        for (int a0 = 0; a0 < 9; a0++)
            for (int b0 = a0; b0 < 9; b0++) { if (idx == q) { a = a0; b = b0; } idx++; }
        qa[q] = a; qb[q] = b;
    }
    __syncthreads();

    for (int task = blk * 256 + t; task < 2640 + 360; task += 8 * 256) {
        if (task < 2640) {               // cubic: og(4) * m(165) * k(4)
            int og = task / 660;
            int r  = task - og * 660;
            int m  = r >> 2, k = r & 3;
            int a = ta[m], b = tb[m], d = td[m];
            const float* U3 = (og == 0) ? U3_0e : U3_1o;
            int o = (og == 0) ? 0 : og - 1;
            const float* Ub = U3 + (size_t)o * 2916;   // [p][q][i][k] strides 324/36/4/1
            #define U3AT(p,q,i) Ub[((p)*9+(q))*36 + (i)*4 + k]
            float sum = U3AT(a,b,d) + U3AT(a,d,b) + U3AT(b,a,d)
                      + U3AT(b,d,a) + U3AT(d,a,b) + U3AT(d,b,a);
            #undef U3AT
            float sc = (a == b && b == d) ? (1.f/6.f)
                     : ((a == b || b == d || a == d) ? 0.5f : 1.f);
            U3sym[(og * 165 + m) * 4 + k] = sum * sc;
        } else {                          // quad: og(4) * q(45) * k(2)
            int t2 = task - 2640;
            int og = t2 / 90;
            int r  = t2 - og * 90;
            int q  = r >> 1, k = r & 1;
            int a = qa[q], b = qb[q];
            const float* U2 = (og == 0) ? U2_0e : U2_1o;
            int o = (og == 0) ? 0 : og - 1;
            const float* Ub = U2 + (size_t)o * 162;    // [p][i][k] strides 18/2/1
            float sum = Ub[(a*9 + b)*2 + k] + Ub[(b*9 + a)*2 + k];
            if (a == b) sum *= 0.5f;
            U2sym[(og * 45 + q) * 2 + k] = sum;
        }
    }
}

// ---------------------------------------------------------------------------
// Kernel 2: main contraction (round-5 structure, proven no-spill) with the
// k_coeff computation FUSED as a per-block preamble: each block computes its
// 876 cfs entries directly from U3sym/U2sym/U1/W (all L2-resident, same float
// ops and order as the old k_coeff -> bitwise-identical results). Deletes the
// k_coeff kernel, its launch gap, and the 9 MB coeff global round-trip.
// Contraction: REAL LOOPS (#pragma unroll 1), x in LDS float2[i][tid],
// wave-uniform broadcast ds_read_b128 for coefficients. f: [n][c][og] float4.
// ---------------------------------------------------------------------------
__global__ __launch_bounds__(256) void k_main(const float* __restrict__ x,
        const int* __restrict__ cnt, const int* __restrict__ list,
        const float* __restrict__ U3sym, const float* __restrict__ U2sym,
        const float* __restrict__ U1_0e, const float* __restrict__ U1_1o,
        const float* __restrict__ W3_0e, const float* __restrict__ W3_1o,
        const float* __restrict__ W2_0e, const float* __restrict__ W2_1o,
        const float* __restrict__ W1_0e, const float* __restrict__ W1_1o,
        float* __restrict__ fout) {
    __shared__ float  cfs[NMONO * 4];        // 3504 B
    __shared__ float2 xsh[9 * 256];          // 18432 B, [i][tid]
    int bx   = blockIdx.x;
    int tile = bx / NBLK;
    int blk  = bx - tile * NBLK;
    int s = blk >> 7, c = blk & 127;
    int n = cnt[s];
    if (tile * 512 >= n) return;             // block-uniform exit (before sync)

    int tid = threadIdx.x;

    // ---- coefficient preamble (was k_coeff) ----
    for (int e = tid; e < NMONO * 4; e += 256) {
        int m = e >> 2, og = e & 3;
        float val;
        if (m < NCUB) {
            const float* W3 = (og == 0) ? W3_0e : W3_1o;   // [s][k][c] strides 512/128/1
            const float* u  = U3sym + (og * 165 + m) * 4;
            val = u[0] * W3[s*512 +       c] + u[1] * W3[s*512 + 128 + c]
                + u[2] * W3[s*512 + 256 + c] + u[3] * W3[s*512 + 384 + c];
        } else if (m < NCUB + NQUAD) {
            int q = m - NCUB;
            const float* W2 = (og == 0) ? W2_0e : W2_1o;   // [s][k][c] strides 256/128/1
            const float* u  = U2sym + (og * 45 + q) * 2;
            val = u[0] * W2[s*256 + c] + u[1] * W2[s*256 + 128 + c];
        } else {
            int l = m - (NCUB + NQUAD);
            const float* U1 = (og == 0) ? U1_0e : U1_1o;   // [o][i][k=1]
            const float* W1 = (og == 0) ? W1_0e : W1_1o;   // [s][1][c]
            int o = (og == 0) ? 0 : og - 1;
            val = U1[o * 9 + l] * W1[s * 128 + c];
        }
        cfs[e] = val;
    }

    // ---- x staging (round-5, unchanged) ----
    const int* __restrict__ lst = list + s * N_NODES;
    int i0 = tile * 512 + tid;
    int i1 = i0 + 256;
    int b0 = lst[i0 < n ? i0 : 0];
    int b1 = lst[i1 < n ? i1 : 0];
    const float* xp0 = x + ((size_t)b0 * C_CH + c) * 9;
    const float* xp1 = x + ((size_t)b1 * C_CH + c) * 9;
    #pragma unroll
    for (int i = 0; i < 9; i++)
        xsh[i * 256 + tid] = make_float2(xp0[i], xp1[i]);
    __syncthreads();

    // ---- contraction (round-5, unchanged) ----
    float a0[4] = {0.f, 0.f, 0.f, 0.f};
    float a1[4] = {0.f, 0.f, 0.f, 0.f};
    int mcub = 0, mquad = 0;

    #pragma unroll 1
    for (int a = 0; a < 9; a++) {
        float2 xa = xsh[a * 256 + tid];
        {   // linear term
            float4 cl = *(const float4*)&cfs[(210 + a) * 4];
            a0[0] = fmaf(cl.x, xa.x, a0[0]);  a1[0] = fmaf(cl.x, xa.y, a1[0]);
            a0[1] = fmaf(cl.y, xa.x, a0[1]);  a1[1] = fmaf(cl.y, xa.y, a1[1]);
            a0[2] = fmaf(cl.z, xa.x, a0[2]);  a1[2] = fmaf(cl.z, xa.y, a1[2]);
            a0[3] = fmaf(cl.w, xa.x, a0[3]);  a1[3] = fmaf(cl.w, xa.y, a1[3]);
        }
        #pragma unroll 1
        for (int b = a; b < 9; b++) {
            float2 xb = xsh[b * 256 + tid];
            float p0 = xa.x * xb.x, p1 = xa.y * xb.y;
            {
                float4 cq = *(const float4*)&cfs[(165 + mquad) * 4]; mquad++;
                a0[0] = fmaf(cq.x, p0, a0[0]);  a1[0] = fmaf(cq.x, p1, a1[0]);
                a0[1] = fmaf(cq.y, p0, a0[1]);  a1[1] = fmaf(cq.y, p1, a1[1]);
                a0[2] = fmaf(cq.z, p0, a0[2]);  a1[2] = fmaf(cq.z, p1, a1[2]);
                a0[3] = fmaf(cq.w, p0, a0[3]);  a1[3] = fmaf(cq.w, p1, a1[3]);
            }
            #pragma unroll 1
            for (int d = b; d < 9; d++) {
                float2 xd = xsh[d * 256 + tid];
                float4 c3 = *(const float4*)&cfs[mcub * 4]; mcub++;
                float q0 = p0 * xd.x, q1 = p1 * xd.y;
                a0[0] = fmaf(c3.x, q0, a0[0]);  a1[0] = fmaf(c3.x, q1, a1[0]);
                a0[1] = fmaf(c3.y, q0, a0[1]);  a1[1] = fmaf(c3.y, q1, a1[1]);
                a0[2] = fmaf(c3.z, q0, a0[2]);  a1[2] = fmaf(c3.z, q1, a1[2]);
                a0[3] = fmaf(c3.w, q0, a0[3]);  a1[3] = fmaf(c3.w, q1, a1[3]);
            }
        }
    }
    if (i0 < n) *(float4*)&fout[((size_t)b0 * C_CH + c) * 4] = make_float4(a0[0], a0[1], a0[2], a0[3]);
    if (i1 < n) *(float4*)&fout[((size_t)b1 * C_CH + c) * 4] = make_float4(a1[0], a1[1], a1[2], a1[3]);
}

// ---------------------------------------------------------------------------
// Kernel 3: epilogue linear (round-0/5 version, unchanged).
// ---------------------------------------------------------------------------
__global__ __launch_bounds__(256) void k_epi(const float* __restrict__ f,
        const float* __restrict__ W0, const float* __restrict__ W1,
        const float* __restrict__ bias, float* __restrict__ out) {
    __shared__ float smem[128 * 65];        // ftile [c][n(64)+pad]; reused as trbuf [j][n]
    int bx = blockIdx.x;
    int ntile = bx >> 3, jg = bx & 7;       // 64 n-tiles x 8 j-groups of 64
    int n0 = ntile * 64;
    int t  = threadIdx.x;
    int o  = jg >> 1;                        // output component 0..3 (uniform per block)

    #pragma unroll
    for (int r = 0; r < 32; ++r) {
        int flat = r * 256 + t;              // 8192 = 64n * 128c
        int n = flat >> 7, c = flat & 127;
        smem[c * 65 + n] = f[(size_t)(n0 + n) * 512 + c * 4 + o];
    }
    __syncthreads();

    int w    = __builtin_amdgcn_readfirstlane((int)(t >> 6));
    int lane = t & 63;
    int mb   = (jg & 1) * 64 + w * 16;       // wave's m base (uniform)
    const float* __restrict__ Wsel = (o == 0) ? W0 : W1;

    float acc[16];
    #pragma unroll
    for (int jj = 0; jj < 16; jj++) acc[jj] = 0.f;

    #pragma unroll 4
    for (int c = 0; c < 128; ++c) {
        float fv = smem[c * 65 + lane];
        #pragma unroll
        for (int jj = 0; jj < 16; jj++)
            acc[jj] = fmaf(fv, Wsel[c * 128 + mb + jj], acc[jj]);
    }
    __syncthreads();

    const float scale = 0.08838834764831845f; // 1/sqrt(128)
    #pragma unroll
    for (int jj = 0; jj < 16; jj++) {
        float v = acc[jj] * scale;
        if (o == 0) v += bias[mb + jj];
        smem[(w * 16 + jj) * 65 + lane] = v;  // trbuf[j_local][n]
    }
    __syncthreads();

    #pragma unroll
    for (int r = 0; r < 16; ++r) {
        int flat = r * 256 + t;               // 4096 = 64j * 64n
        int jl = flat & 63, n = flat >> 6;
        int m  = (jg & 1) * 64 + jl;
        int col = (o == 0) ? m : (128 + m * 3 + (o - 1));
        out[(size_t)(n0 + n) * 512 + col] = smem[jl * 65 + n];
    }
}

extern "C" void kernel_launch(void* const* d_in, const int* in_sizes, int n_in,
                              void* d_out, int out_size, void* d_ws, size_t ws_size,
                              hipStream_t stream) {
    const float* x     = (const float*)d_in[0];
    const int*   spec  = (const int*)  d_in[1];
    const float* U3_0e = (const float*)d_in[2];
    const float* U2_0e = (const float*)d_in[3];
    const float* U1_0e = (const float*)d_in[4];
    const float* W3_0e = (const float*)d_in[5];
    const float* W2_0e = (const float*)d_in[6];
    const float* W1_0e = (const float*)d_in[7];
    const float* U3_1o = (const float*)d_in[8];
    const float* U2_1o = (const float*)d_in[9];
    const float* U1_1o = (const float*)d_in[10];
    const float* W3_1o = (const float*)d_in[11];
    const float* W2_1o = (const float*)d_in[12];
    const float* W1_1o = (const float*)d_in[13];
    const float* Wlin0 = (const float*)d_in[14];
    const float* Wlin1 = (const float*)d_in[15];
    const float* bias0 = (const float*)d_in[16];
    float* out = (float*)d_out;

    char* ws = (char*)d_ws;
    int*   cnt   = (int*)  (ws + WS_CNT);
    int*   list  = (int*)  (ws + WS_LIST);
    float* U3sym = (float*)(ws + WS_U3SYM);
    float* U2sym = (float*)(ws + WS_U2SYM);
    float* f     = (float*)(ws + WS_F);
    (void)in_sizes; (void)n_in; (void)out_size; (void)ws_size;

    // K1: blocks 0..7 = symmetrize U3/U2; block 8 = species bucketing.
    hipLaunchKernelGGL(k_prep, dim3(9), dim3(256), 0, stream,
                       U3_0e, U3_1o, U2_0e, U2_1o, spec, cnt, list, U3sym, U2sym);
    // K2: coeff-fused contraction. Grid covers (tile, s, c); dead tiles exit.
    hipLaunchKernelGGL(k_main, dim3(NBLK * NTILE), dim3(256), 0, stream,
                       x, cnt, list, U3sym, U2sym, U1_0e, U1_1o,
                       W3_0e, W3_1o, W2_0e, W2_1o, W1_0e, W1_1o, f);
    // K3: epilogue linear.
    hipLaunchKernelGGL(k_epi, dim3(512), dim3(256), 0, stream,
                       f, Wlin0, Wlin1, bias0, out);
}